// Round 1
// baseline (304.161 us; speedup 1.0000x reference)
//
#include <hip/hip_runtime.h>

// out[b, m, r] = x[b, ind[r,m]] * filters[r, ind[r,m]]
// B=1024, D_ALL=65536 cols in x/filters, r in [0,512), m in [0,128)
// out layout: [B][128][512] fp32 (r contiguous)

constexpr int D_ROW  = 128;            // MAP_SIZE (m)
constexpr int D_COL  = 512;            // OUT_ROW (r)
constexpr int D_ALL  = D_ROW * D_COL;  // 65536
constexpr int BATCH  = 1024;

// Build transposed tables in workspace (output layout, so main-kernel reads coalesce):
//   ind_t[m*512 + r] = ind[r*128 + m]
//   w_t  [m*512 + r] = filters[r*65536 + ind[r*128 + m]]
__global__ void __launch_bounds__(256)
build_tables(const float* __restrict__ filters,
             const int*   __restrict__ ind,
             int*   __restrict__ ind_t,
             float* __restrict__ w_t) {
    int t = blockIdx.x * 256 + threadIdx.x;   // 0 .. 65535
    if (t >= D_ALL) return;
    int m = t >> 9;          // t / 512
    int r = t & 511;         // t % 512
    int idx = ind[r * D_ROW + m];
    ind_t[t] = idx;
    w_t[t]   = filters[(size_t)r * D_ALL + idx];
}

// Main kernel: 1 float4 of output per thread. 65536 blocks x 256 threads x 4 elems.
// Each batch row of out (65536 elems) = 64 consecutive work chunks; the XCD
// swizzle keeps those 64 chunks on one XCD so the 256 KB x-row is fetched to
// that XCD's L2 once and all gathers hit it.
__global__ void __launch_bounds__(256)
map_kernel(const float* __restrict__ x,
           const int*   __restrict__ ind_t,
           const float* __restrict__ w_t,
           float*       __restrict__ out) {
    unsigned bid = blockIdx.x;
    unsigned nwg = gridDim.x;                       // 65536, divisible by 8
    unsigned w   = (bid & 7u) * (nwg >> 3) + (bid >> 3);   // bijective XCD swizzle

    size_t o = ((size_t)w * 256u + threadIdx.x) * 4u;      // out element offset
    unsigned b   = (unsigned)(o >> 16);                    // / 65536
    unsigned rem = (unsigned)(o & 65535u);                 // (m*512 + r)

    int4   i4 = *reinterpret_cast<const int4*>(ind_t + rem);
    float4 w4 = *reinterpret_cast<const float4*>(w_t  + rem);
    const float* xb = x + ((size_t)b << 16);

    float4 r4;
    r4.x = xb[i4.x] * w4.x;
    r4.y = xb[i4.y] * w4.y;
    r4.z = xb[i4.z] * w4.z;
    r4.w = xb[i4.w] * w4.w;
    *reinterpret_cast<float4*>(out + o) = r4;
}

// Fallback if workspace is too small: recompute gathers inline (slower, correct).
__global__ void __launch_bounds__(256)
map_kernel_nows(const float* __restrict__ x,
                const float* __restrict__ filters,
                const int*   __restrict__ ind,
                float*       __restrict__ out) {
    size_t o = (size_t)blockIdx.x * 256 + threadIdx.x;
    if (o >= (size_t)BATCH * D_ALL) return;
    unsigned b   = (unsigned)(o >> 16);
    unsigned rem = (unsigned)(o & 65535u);
    unsigned m = rem >> 9, r = rem & 511u;
    int idx = ind[r * D_ROW + m];
    out[o] = x[((size_t)b << 16) + idx] * filters[(size_t)r * D_ALL + idx];
}

extern "C" void kernel_launch(void* const* d_in, const int* in_sizes, int n_in,
                              void* d_out, int out_size, void* d_ws, size_t ws_size,
                              hipStream_t stream) {
    const float* x       = (const float*)d_in[0];
    const float* filters = (const float*)d_in[1];
    const int*   ind     = (const int*)d_in[2];
    float*       out     = (float*)d_out;

    const size_t need = (size_t)D_ALL * (sizeof(int) + sizeof(float));  // 512 KB
    if (ws_size >= need) {
        int*   ind_t = (int*)d_ws;
        float* w_t   = (float*)((char*)d_ws + (size_t)D_ALL * sizeof(int));
        build_tables<<<D_ALL / 256, 256, 0, stream>>>(filters, ind, ind_t, w_t);
        map_kernel<<<(BATCH * D_ALL) / (256 * 4), 256, 0, stream>>>(x, ind_t, w_t, out);
    } else {
        map_kernel_nows<<<(BATCH * (size_t)D_ALL) / 256, 256, 0, stream>>>(
            x, filters, ind, out);
    }
}

// Round 2
// 285.629 us; speedup vs baseline: 1.0649x; 1.0649x over previous
//
#include <hip/hip_runtime.h>

// out[b, m, r] = x[b, ind[r,m]] * filters[r, ind[r,m]]
// B=1024; x row = 65536 fp32 = 256 KB; out row = 65536 fp32 (layout m*512+r)

constexpr int D_ROW  = 128;            // m
constexpr int D_COL  = 512;            // r
constexpr int D_ALL  = D_ROW * D_COL;  // 65536
constexpr int BATCH  = 1024;
constexpr int HALF   = 32768;          // floats staged per phase (128 KB LDS)

// Tables in output layout (rem = m*512+r): ind16[rem] = ind[r,m] (u16),
// w_t[rem] = filters[r, ind[r,m]]. Built once per call; reused by all 1024 rows.
__global__ void __launch_bounds__(256)
build_tables(const float* __restrict__ filters,
             const int*   __restrict__ ind,
             ushort* __restrict__ ind16,
             float*  __restrict__ w_t) {
    int t = blockIdx.x * 256 + threadIdx.x;   // 0 .. 65535
    if (t >= D_ALL) return;
    int m = t >> 9;
    int r = t & 511;
    int idx = ind[r * D_ROW + m];
    ind16[t] = (ushort)idx;
    w_t[t]   = filters[(size_t)r * D_ALL + idx];
}

// One block per batch row. Stage x-row in two 128 KB halves; per phase,
// process outputs whose gather index lies in the staged half. All global
// traffic is streaming/coalesced; the random access is LDS-only.
__global__ void __launch_bounds__(1024)
map2(const float* __restrict__ x,
     const ushort* __restrict__ ind16,
     const float* __restrict__ w_t,
     float* __restrict__ out) {
    __shared__ float xs[HALF];
    const int b = blockIdx.x;
    const int t = threadIdx.x;                 // 0..1023
    const float* xb = x + ((size_t)b << 16);
    float*       ob = out + ((size_t)b << 16);

    #pragma unroll 1
    for (int p = 0; p < 2; ++p) {
        // ---- stage 128 KB: coalesced float4 stream ----
        const float4* src = reinterpret_cast<const float4*>(xb) + p * (HALF / 4 / 1) / 1;
        // (src points at phase base: p * 8192 float4s)
        src = reinterpret_cast<const float4*>(xb) + p * (HALF / 4);
        float4* dst = reinterpret_cast<float4*>(xs);
        #pragma unroll
        for (int i = 0; i < HALF / 4 / 1024; ++i)        // 8 iterations
            dst[i * 1024 + t] = src[i * 1024 + t];
        __syncthreads();

        // ---- compute: 4 consecutive outputs per thread per jj ----
        const unsigned half = (unsigned)p << 15;
        #pragma unroll 4
        for (int jj = 0; jj < 16; ++jj) {
            const int base = jj * 4096 + t * 4;          // element offset in row
            ushort4 i4 = *reinterpret_cast<const ushort4*>(ind16 + base);
            float4  w4 = *reinterpret_cast<const float4*>(w_t  + base);
            if ((i4.x & 32768u) == half) ob[base + 0] = xs[i4.x & 32767u] * w4.x;
            if ((i4.y & 32768u) == half) ob[base + 1] = xs[i4.y & 32767u] * w4.y;
            if ((i4.z & 32768u) == half) ob[base + 2] = xs[i4.z & 32767u] * w4.z;
            if ((i4.w & 32768u) == half) ob[base + 3] = xs[i4.w & 32767u] * w4.w;
        }
        __syncthreads();   // before next phase overwrites xs
    }
}

// Fallback if workspace too small: direct gather (round-0 style, correct).
__global__ void __launch_bounds__(256)
map_kernel_nows(const float* __restrict__ x,
                const float* __restrict__ filters,
                const int*   __restrict__ ind,
                float*       __restrict__ out) {
    size_t o = (size_t)blockIdx.x * 256 + threadIdx.x;
    if (o >= (size_t)BATCH * D_ALL) return;
    unsigned b   = (unsigned)(o >> 16);
    unsigned rem = (unsigned)(o & 65535u);
    unsigned m = rem >> 9, r = rem & 511u;
    int idx = ind[r * D_ROW + m];
    out[o] = x[((size_t)b << 16) + idx] * filters[(size_t)r * D_ALL + idx];
}

extern "C" void kernel_launch(void* const* d_in, const int* in_sizes, int n_in,
                              void* d_out, int out_size, void* d_ws, size_t ws_size,
                              hipStream_t stream) {
    const float* x       = (const float*)d_in[0];
    const float* filters = (const float*)d_in[1];
    const int*   ind     = (const int*)d_in[2];
    float*       out     = (float*)d_out;

    const size_t need = (size_t)D_ALL * sizeof(float) + (size_t)D_ALL * sizeof(ushort);
    if (ws_size >= need) {
        float*  w_t   = (float*)d_ws;                              // 256 KB
        ushort* ind16 = (ushort*)((char*)d_ws + (size_t)D_ALL * 4); // 128 KB
        build_tables<<<D_ALL / 256, 256, 0, stream>>>(filters, ind, ind16, w_t);
        map2<<<BATCH, 1024, 0, stream>>>(x, ind16, w_t, out);
    } else {
        map_kernel_nows<<<(BATCH * (size_t)D_ALL) / 256, 256, 0, stream>>>(
            x, filters, ind, out);
    }
}

// Round 3
// 151.643 us; speedup vs baseline: 2.0058x; 1.8836x over previous
//
#include <hip/hip_runtime.h>
#include <hip/hip_fp16.h>

// out[b, m, r] = x[b, ind[r,m]] * filters[r, ind[r,m]]
// B=1024; x row = 65536 fp32; out row = 65536 fp32, layout rem = m*512 + r.
// Strategy: stage the ENTIRE x row in LDS as fp16 (128 KB) -> single-phase,
// fully coalesced float4 output stores, random access confined to LDS.
// 4 rows per block, register-prefetch of row k+1 overlaps compute of row k.

constexpr int D_ROW = 128;
constexpr int D_COL = 512;
constexpr int D_ALL = D_ROW * D_COL;   // 65536
constexpr int BATCH = 1024;
constexpr int ROWS_PER_BLK = 4;

// Tables in output layout: ind16[m*512+r] = ind[r,m]; w_t[m*512+r] = filters[r, ind[r,m]]
__global__ void __launch_bounds__(256)
build_tables(const float* __restrict__ filters,
             const int*   __restrict__ ind,
             ushort* __restrict__ ind16,
             float*  __restrict__ w_t) {
    int t = blockIdx.x * 256 + threadIdx.x;
    if (t >= D_ALL) return;
    int m = t >> 9;
    int r = t & 511;
    int idx = ind[r * D_ROW + m];
    ind16[t] = (ushort)idx;
    w_t[t]   = filters[(size_t)r * D_ALL + idx];
}

__global__ void __launch_bounds__(1024)
map3(const float* __restrict__ x,
     const ushort* __restrict__ ind16,
     const float* __restrict__ w_t,
     float* __restrict__ out) {
    __shared__ __half xs[D_ALL];               // 128 KB: full row as fp16
    const int t = threadIdx.x;                  // 0..1023
    const int row0 = blockIdx.x * ROWS_PER_BLK;

    // Prologue: load row0 into registers (16 x float4 = 64 VGPR)
    float4 buf[16];
    {
        const float4* src = reinterpret_cast<const float4*>(x + ((size_t)row0 << 16));
        #pragma unroll
        for (int i = 0; i < 16; ++i) buf[i] = src[i * 1024 + t];
    }

    for (int k = 0; k < ROWS_PER_BLK; ++k) {
        // Write buffered row into LDS as fp16 (convert here so the prefetch
        // phase below stays pure-load and can stay in flight during compute).
        #pragma unroll
        for (int i = 0; i < 16; ++i) {
            __half2 h0 = __floats2half2_rn(buf[i].x, buf[i].y);
            __half2 h1 = __floats2half2_rn(buf[i].z, buf[i].w);
            __half2* dst = reinterpret_cast<__half2*>(xs) + (i * 1024 + t) * 2;
            dst[0] = h0;
            dst[1] = h1;
        }
        __syncthreads();

        // Prefetch next row into regs; independent of compute below, so the
        // loads stay outstanding until the ds_write at the top of next iter.
        if (k + 1 < ROWS_PER_BLK) {
            const float4* src = reinterpret_cast<const float4*>(
                x + ((size_t)(row0 + k + 1) << 16));
            #pragma unroll
            for (int i = 0; i < 16; ++i) buf[i] = src[i * 1024 + t];
        }

        // Compute row k: 64 outputs/thread, full float4 stores (no predication)
        float* ob = out + ((size_t)(row0 + k) << 16);
        #pragma unroll 2
        for (int j = 0; j < 16; ++j) {
            const int base = j * 4096 + t * 4;
            ushort4 i4 = *reinterpret_cast<const ushort4*>(ind16 + base);
            float4  w4 = *reinterpret_cast<const float4*>(w_t  + base);
            float4 r;
            r.x = __half2float(xs[i4.x]) * w4.x;
            r.y = __half2float(xs[i4.y]) * w4.y;
            r.z = __half2float(xs[i4.z]) * w4.z;
            r.w = __half2float(xs[i4.w]) * w4.w;
            *reinterpret_cast<float4*>(ob + base) = r;
        }
        __syncthreads();   // xs reused next iteration
    }
}

// Fallback if workspace too small: direct gather (correct, slow).
__global__ void __launch_bounds__(256)
map_kernel_nows(const float* __restrict__ x,
                const float* __restrict__ filters,
                const int*   __restrict__ ind,
                float*       __restrict__ out) {
    size_t o = (size_t)blockIdx.x * 256 + threadIdx.x;
    if (o >= (size_t)BATCH * D_ALL) return;
    unsigned b   = (unsigned)(o >> 16);
    unsigned rem = (unsigned)(o & 65535u);
    unsigned m = rem >> 9, r = rem & 511u;
    int idx = ind[r * D_ROW + m];
    out[o] = x[((size_t)b << 16) + idx] * filters[(size_t)r * D_ALL + idx];
}

extern "C" void kernel_launch(void* const* d_in, const int* in_sizes, int n_in,
                              void* d_out, int out_size, void* d_ws, size_t ws_size,
                              hipStream_t stream) {
    const float* x       = (const float*)d_in[0];
    const float* filters = (const float*)d_in[1];
    const int*   ind     = (const int*)d_in[2];
    float*       out     = (float*)d_out;

    const size_t need = (size_t)D_ALL * sizeof(float) + (size_t)D_ALL * sizeof(ushort);
    if (ws_size >= need) {
        float*  w_t   = (float*)d_ws;                                // 256 KB
        ushort* ind16 = (ushort*)((char*)d_ws + (size_t)D_ALL * 4);  // 128 KB
        build_tables<<<D_ALL / 256, 256, 0, stream>>>(filters, ind, ind16, w_t);
        map3<<<BATCH / ROWS_PER_BLK, 1024, 0, stream>>>(x, ind16, w_t, out);
    } else {
        map_kernel_nows<<<(BATCH * (size_t)D_ALL) / 256, 256, 0, stream>>>(
            x, filters, ind, out);
    }
}